// Round 10
// baseline (363.092 us; speedup 1.0000x reference)
//
#include <hip/hip_runtime.h>
#include <hip/hip_bf16.h>

// Model: one_hot -> 3x Conv2D(5,(4,4),(1,2),SAME) -> [B,S=1024,D=20]
//        -> 3x causal self-attention -> flatten -> 3x Dense(10)
// B=64, L=8192, S=1024, D=20.
// R23 (198.5): attn 512-thr (q-subtile,t-half). R25 (199.2): fragment-major
//      V, no attn LDS staging. R26 (202, null): conv parallelize. R27 (218):
//      in-kernel t-split. R28 (207.8): attn software pipeline (+16 VGPR ->
//      occupancy step / spill). ALL attn-internal levers null-or-negative ->
//      plateau is launch count + memory round-trips (R17/R21 evidence).
// R29: FUSE conv12 + conv3_proj into ONE kernel. Each block (256 conv3
//      outputs) stages its 514 c2 columns in LDS (43KB; exact conv12 FMA
//      order -> bit-identical), one sync, then conv3+proj from LDS.
//      Kills the c2 HBM round-trip (47MB, ~7us) + one launch (~3us) + the
//      old conv3_proj's 1-wave/SIMD latency exposure. Attn = R25 verbatim
//      (R28 pipelining reverted). 5 launches total.

#define B_ 64
#define L_ 8192
#define S_ 1024
#define D_ 20

typedef unsigned short ushort_t;
typedef __attribute__((ext_vector_type(8))) short short8_t;  // 8 bf16 (4 VGPRs)
typedef __attribute__((ext_vector_type(4))) short short4_t;  // 4 bf16 (2 VGPRs)
typedef __attribute__((ext_vector_type(4))) float f32x4_t;   // MFMA C/D

__device__ __forceinline__ ushort_t f2bf(float f) {          // RNE fp32->bf16
  unsigned u = __float_as_uint(f);
  return (ushort_t)((u + 0x7fffu + ((u >> 16) & 1u)) >> 16);
}
__device__ __forceinline__ float bf2f(ushort_t h) {
  return __uint_as_float(((unsigned)h) << 16);
}

// -------- fused conv1+conv2+conv3+proj (+ W1 transpose tail) -------------
// Block = 256 conv3 outputs (b = blk>>2, wo in [wo0, wo0+256)). Stage the
// 514 c2 columns [2*wo0-1 .. 2*wo0+512] into LDS (each computed with the
// exact conv12 per-column body -> bit-identical to the old two-kernel path;
// out-of-range columns are zeros = conv3 SAME padding), then conv3 + QKV
// projection straight from LDS. c2 never touches HBM.
__global__ __launch_bounds__(256) void conv_fused_kernel(
    const int* __restrict__ inp,
    const float* __restrict__ W1c, const float* __restrict__ B1c,
    const float* __restrict__ W2c, const float* __restrict__ B2c,
    const float* __restrict__ W3c, const float* __restrict__ B3c,
    const float* __restrict__ Kw,  const float* __restrict__ Qw,
    const float* __restrict__ Vw,
    ushort_t* __restrict__ Qb, ushort_t* __restrict__ Kb,
    ushort_t* __restrict__ Vf,                    // Vf[b][64][20][16]
    const float* __restrict__ W1d,                // dense W1 [20480,10]
    float* __restrict__ W1T) {                    // [10,20480]
  __shared__ float w1s[80], b1s[5], w2s[400], b2s[5];
  __shared__ float ws3[400], bs3[5];
  __shared__ float kws[400], qws[400], vws[400];
  __shared__ float c2s[514 * 21];                 // staged c2 columns (pad 21)
  const int tid = threadIdx.x;
  const int blk = blockIdx.x;                     // 256 blocks
  for (int i = tid; i < 400; i += 256) {
    w2s[i] = W2c[i]; ws3[i] = W3c[i];
    kws[i] = Kw[i];  qws[i] = Qw[i];  vws[i] = Vw[i];
  }
  if (tid < 80)       w1s[tid]      = W1c[tid];
  else if (tid < 85)  b1s[tid - 80] = B1c[tid - 80];
  else if (tid < 90)  b2s[tid - 85] = B2c[tid - 85];
  else if (tid < 95)  bs3[tid - 90] = B3c[tid - 90];
  __syncthreads();
  const int b   = blk >> 2;
  const int wo0 = (blk & 3) << 8;
  const int* ib = inp + (size_t)b * L_;
  // ---- stage c2 columns [2*wo0-1 .. 2*wo0+512] (exact conv12 body) ----
  for (int sidx = tid; sidx < 514; sidx += 256) {
    const int wi = 2 * wo0 - 1 + sidx;
    float acc[4][5];
    if (wi >= 0 && wi < 2048) {
      int iv[10];
#pragma unroll
      for (int t = 0; t < 10; ++t) {
        int g = 4 * wi - 3 + t;
        iv[t] = (g >= 0 && g < L_) ? ib[g] : -100;  // sentinel
      }
      float val[4][4][5];                           // [hi][pos][ci]
#pragma unroll
      for (int pos = 0; pos < 4; ++pos) {
        const int w1 = 2 * wi - 1 + pos;
        const bool okp = (w1 >= 0 && w1 < 4096);    // conv2 SAME pad -> 0
#pragma unroll
        for (int hi = 0; hi < 4; ++hi)
#pragma unroll
          for (int ci = 0; ci < 5; ++ci) val[hi][pos][ci] = okp ? b1s[ci] : 0.f;
        if (okp) {
#pragma unroll
          for (int kw = 0; kw < 4; ++kw) {
            const int gw = 2 * w1 - 1 + kw;
            if (gw >= 0 && gw < L_) {
              const int v = iv[2 * pos + kw];
#pragma unroll
              for (int hi = 0; hi < 4; ++hi) {
                const int kh = v - hi + 1;
                if (kh >= 0 && kh < 4) {
#pragma unroll
                  for (int ci = 0; ci < 5; ++ci)
                    val[hi][pos][ci] += w1s[(kh * 4 + kw) * 5 + ci];
                }
              }
            }
          }
        }
      }
#pragma unroll
      for (int h = 0; h < 4; ++h)
#pragma unroll
        for (int c = 0; c < 5; ++c) acc[h][c] = b2s[c];
#pragma unroll
      for (int kh = 0; kh < 4; ++kh)
#pragma unroll
        for (int kw = 0; kw < 4; ++kw)
#pragma unroll
          for (int ci = 0; ci < 5; ++ci) {
            const float* wp = w2s + ((kh * 4 + kw) * 5 + ci) * 5;
            float w0 = wp[0], w1v = wp[1], w2v = wp[2], w3v = wp[3], w4v = wp[4];
#pragma unroll
            for (int h = 0; h < 4; ++h) {
              int hi = h - 1 + kh;
              if (hi >= 0 && hi < 4) {
                float x = val[hi][kw][ci];
                acc[h][0] += w0 * x;  acc[h][1] += w1v * x; acc[h][2] += w2v * x;
                acc[h][3] += w3v * x; acc[h][4] += w4v * x;
              }
            }
          }
    } else {
#pragma unroll
      for (int h = 0; h < 4; ++h)
#pragma unroll
        for (int c = 0; c < 5; ++c) acc[h][c] = 0.f;  // conv3 SAME padding
    }
#pragma unroll
    for (int h = 0; h < 4; ++h)
#pragma unroll
      for (int c = 0; c < 5; ++c) c2s[sidx * 21 + h * 5 + c] = acc[h][c];
  }
  __syncthreads();
  // ---- conv3 + proj (exact conv3_proj body, vals from LDS) ----
  const int wo = wo0 + tid;
  const int r  = (b << 10) + wo;
  float val[4][4][5];
#pragma unroll
  for (int kwp = 0; kwp < 4; ++kwp) {
    const int lidx = 2 * tid + kwp;               // = wi - (2*wo0 - 1)
#pragma unroll
    for (int hi = 0; hi < 4; ++hi)
#pragma unroll
      for (int ci = 0; ci < 5; ++ci)
        val[hi][kwp][ci] = c2s[lidx * 21 + hi * 5 + ci];
  }
  float acc[4][5];
#pragma unroll
  for (int h = 0; h < 4; ++h)
#pragma unroll
    for (int c = 0; c < 5; ++c) acc[h][c] = bs3[c];
#pragma unroll
  for (int kh = 0; kh < 4; ++kh)
#pragma unroll
    for (int kwp = 0; kwp < 4; ++kwp)
#pragma unroll
      for (int ci = 0; ci < 5; ++ci) {
        const float* wp = ws3 + ((kh * 4 + kwp) * 5 + ci) * 5;
        float w0 = wp[0], w1 = wp[1], w2 = wp[2], w3 = wp[3], w4 = wp[4];
#pragma unroll
        for (int h = 0; h < 4; ++h) {
          int hi = h - 1 + kh;
          if (hi >= 0 && hi < 4) {
            float x = val[hi][kwp][ci];
            acc[h][0] += w0 * x; acc[h][1] += w1 * x; acc[h][2] += w2 * x;
            acc[h][3] += w3 * x; acc[h][4] += w4 * x;
          }
        }
      }
  float x[D_];
#pragma unroll
  for (int h = 0; h < 4; ++h)
#pragma unroll
    for (int c = 0; c < 5; ++c) x[h * 5 + c] = acc[h][c];
  float q[D_], k[D_], v[D_];
#pragma unroll
  for (int j = 0; j < D_; ++j) { q[j] = 0.f; k[j] = 0.f; v[j] = 0.f; }
#pragma unroll
  for (int i = 0; i < D_; ++i) {
#pragma unroll
    for (int j = 0; j < D_; ++j) {
      q[j] += x[i] * qws[i * D_ + j];
      k[j] += x[i] * kws[i * D_ + j];
      v[j] += x[i] * vws[i * D_ + j];
    }
  }
  const float sc = 0.22360679774997896f;  // 1/sqrt(20)
  ushort_t qt[32], kt[32];
#pragma unroll
  for (int j = 0; j < D_; ++j) { qt[j] = f2bf(q[j] * sc); kt[j] = f2bf(k[j]); }
#pragma unroll
  for (int j = D_; j < 32; ++j) { qt[j] = 0; kt[j] = 0; }
  int4* qd = (int4*)(Qb + (size_t)r * 32);
  int4* kd = (int4*)(Kb + (size_t)r * 32);
#pragma unroll
  for (int j = 0; j < 4; ++j) {
    qd[j] = *(const int4*)(qt + 8 * j);
    kd[j] = *(const int4*)(kt + 8 * j);
  }
  // fragment-major V: Vf[b][wo>>4][d][wo&15]
  ushort_t* vbase = Vf + ((size_t)b * 64 + (wo >> 4)) * 320 + (wo & 15);
#pragma unroll
  for (int d = 0; d < D_; ++d) vbase[d * 16] = f2bf(v[d]);
  // ---- tail: W1 transpose (grid-stride over 204800 elements) ----
  for (int t2 = blk * 256 + tid; t2 < 204800; t2 += 65536) {
    int col = t2 / 20480, i2 = t2 - col * 20480;
    W1T[t2] = W1d[i2 * 10 + col];
  }
}

// ---------------- causal attention: 8 waves = (q-subtile, t-half) ---------
// S^T = mfma_16x16x32(Kfrag, Qfrag): lane (quad,n): S^T[t=quad*4+r][q=n].
// P^T register layout IS the B-operand of mfma_16x16x16; PV from registers.
// K and Vf both read DIRECT from global, fully coalesced (K: 1KB/wave instr;
// Vf vlo: one 512B segment; vhi: one 128B segment), L2-hot per b.
// No LDS staging at all; FUSE path has ONE barrier total. (R25 verbatim.)
// FUSE=true : epilogue projects O rows -> next layer's Qb2/Kb2/Vf2.
// FUSE=false: epilogue computes dense1 partial -> part2[b][strip][10].
template <bool FUSE>
__global__ __launch_bounds__(512, 8) void attn_kernel(
    const ushort_t* __restrict__ Qb, const ushort_t* __restrict__ Kb,
    const ushort_t* __restrict__ Vf,
    const float* __restrict__ Kw2, const float* __restrict__ Qw2,
    const float* __restrict__ Vw2,
    ushort_t* __restrict__ Qb2, ushort_t* __restrict__ Kb2,
    ushort_t* __restrict__ Vf2,
    const float* __restrict__ W1T,   // !FUSE: [10,20480]
    float* __restrict__ part2) {     // !FUSE: [64,16,10]
  __shared__ float ox[1280];                  // merged O rows [4 subtiles x 320]
  __shared__ float pw_s[FUSE ? 1200 : 4];     // proj weights (FUSE)
  __shared__ float mrgL[64];                  // half1 l partials [sub][n]
  __shared__ float red2[40];                  // !FUSE per-wave dense sums
  const int blk   = blockIdx.x;
  const int b     = blk & 63;                 // blk%8==b%8 -> XCD locality
  const int raw   = blk >> 6;                 // 0..15
  const int rr4   = raw & 3, k4 = raw >> 2;
  const int strip = (k4 == 0) ? rr4 : (k4 == 1) ? 7 - rr4
                  : (k4 == 2) ? 8 + rr4 : 15 - rr4;  // per-CU sum const
  const int q0    = strip * 64;
  const int nt    = q0 + 64;
  const int tid   = threadIdx.x;
  const int w     = tid >> 6;                 // wave 0..7
  const int sub   = w & 3;                    // q-subtile
  const int half  = w >> 2;                   // t-half
  const int lane  = tid & 63;
  const int n     = lane & 15;
  const int quad  = lane >> 4;
  const int qbase = q0 + 16 * sub;
  const int qg    = qbase + n;                // this lane's q column
  if (FUSE) {
    for (int i = tid; i < 1200; i += 512) {
      int m = i / 400, oo = i - m * 400;
      pw_s[i] = (m == 0) ? Kw2[oo] : (m == 1) ? Qw2[oo] : Vw2[oo];
    }
  }
  const ushort_t* KbB  = Kb + (size_t)b * 1024 * 32;
  const ushort_t* VfB  = Vf + (size_t)b * 20480;       // [64][20][16]
  const ushort_t* vloB = VfB + n * 16 + quad * 4;
  const ushort_t* vhiB = VfB + (16 + (n & 3)) * 16 + quad * 4;
  short8_t qfrag = *(const short8_t*)(Qb + ((size_t)(b * 1024 + qbase + n)) * 32 + quad * 8);
  f32x4_t oA = {0.f, 0.f, 0.f, 0.f};          // O^T[d=quad*4+r][q=n]
  f32x4_t oB = {0.f, 0.f, 0.f, 0.f};          // O^T[d=16+quad*4+r][q=n] (quad0)
  const f32x4_t zero = {0.f, 0.f, 0.f, 0.f};
  float lsum = 0.f;
  const int nt2 = nt >> 1;
  const int tlo = half ? nt2 : 0;
  int thi = half ? nt : nt2;
  if (thi > qbase + 16) thi = qbase + 16;     // wave-uniform: skip all-masked
  for (int t0 = tlo; t0 < thi; t0 += 32) {
    short8_t kf0 = *(const short8_t*)(KbB + (size_t)(t0 + n) * 32 + quad * 8);
    short8_t kf1 = *(const short8_t*)(KbB + (size_t)(t0 + 16 + n) * 32 + quad * 8);
#pragma unroll
    for (int c = 0; c < 2; ++c) {
      const int tg = t0 + c * 16 + quad * 4;  // global t of r=0
      f32x4_t s = __builtin_amdgcn_mfma_f32_16x16x32_bf16(c ? kf1 : kf0, qfrag,
                                                          zero, 0, 0, 0);
      ushort_t pk4[4];
#pragma unroll
      for (int r = 0; r < 4; ++r) {
        float p = (tg + r <= qg) ? __expf(s[r]) : 0.f;
        ushort_t h = f2bf(p);
        lsum += bf2f(h);                      // consistent with bf16 P in PV
        pk4[r] = h;
      }
      short4_t pfrag = *(const short4_t*)pk4; // B16-frag: k=quad*4+j, n=q
      const int tb = (t0 >> 4) + c;           // 16-t fragment block index
      short4_t vlo = *(const short4_t*)(vloB + tb * 320);
      short4_t vhi = *(const short4_t*)(vhiB + tb * 320);
      oA = __builtin_amdgcn_mfma_f32_16x16x16bf16_1k(vlo, pfrag, oA, 0, 0, 0);
      oB = __builtin_amdgcn_mfma_f32_16x16x16bf16_1k(vhi, pfrag, oB, 0, 0, 0);
    }
  }
  // l[q=n]: reduce partial sums across the 4 quads
  float l = lsum;
  l += __shfl_xor(l, 16, 64);
  l += __shfl_xor(l, 32, 64);
  float* oxw = ox + sub * 320;
  // ---- merge halves: half1 writes partials (ox layout), half0 adds ----
  if (half) {
#pragma unroll
    for (int r = 0; r < 4; ++r) oxw[n * 20 + quad * 4 + r] = oA[r];
    if (quad == 0) {
#pragma unroll
      for (int r = 0; r < 4; ++r) oxw[n * 20 + 16 + r] = oB[r];
      mrgL[sub * 16 + n] = l;
    }
  }
  __syncthreads();
  if (!half) {
#pragma unroll
    for (int r = 0; r < 4; ++r) oA[r] += oxw[n * 20 + quad * 4 + r];
    if (quad == 0) {
#pragma unroll
      for (int r = 0; r < 4; ++r) oB[r] += oxw[n * 20 + 16 + r];
    }
    l += mrgL[sub * 16 + n];                  // broadcast read per n
    const float inv = 1.f / l;
    // overwrite own region with normalized O
#pragma unroll
    for (int r = 0; r < 4; ++r) oxw[n * 20 + quad * 4 + r] = oA[r] * inv;
    if (quad == 0) {
#pragma unroll
      for (int r = 0; r < 4; ++r) oxw[n * 20 + 16 + r] = oB[r] * inv;
    }
  }
  if (FUSE) {
    if (!half) {
      __asm__ volatile("s_waitcnt lgkmcnt(0)" ::: "memory");  // wave LDS RAW
      const int row  = lane >> 2;     // 0..15
      const int part = lane & 3;      // cols 5*part .. 5*part+4
      float x[D_];
#pragma unroll
      for (int i = 0; i < D_; ++i) x[i] = oxw[row * 20 + i];
      float qv[5], kv[5], vv[5];
#pragma unroll
      for (int jj = 0; jj < 5; ++jj) { qv[jj] = 0.f; kv[jj] = 0.f; vv[jj] = 0.f; }
#pragma unroll
      for (int i = 0; i < D_; ++i) {
        const float xi = x[i];
#pragma unroll
        for (int jj = 0; jj < 5; ++jj) {
          const int j = 5 * part + jj;
          kv[jj] += xi * pw_s[i * 20 + j];          // K block
          qv[jj] += xi * pw_s[400 + i * 20 + j];    // Q block
          vv[jj] += xi * pw_s[800 + i * 20 + j];    // V block
        }
      }
      const float sc = 0.22360679774997896f;
      const int rg = b * 1024 + qbase + row;
      const int s  = rg & 1023;
#pragma unroll
      for (int jj = 0; jj < 5; ++jj) {
        const int j = 5 * part + jj;
        Kb2[(size_t)rg * 32 + j] = f2bf(kv[jj]);
        Qb2[(size_t)rg * 32 + j] = f2bf(qv[jj] * sc);
        Vf2[(size_t)b * 20480 + (size_t)(s >> 4) * 320 + j * 16 + (s & 15)] =
            f2bf(vv[jj]);
      }
      if (part == 0) {
#pragma unroll
        for (int u = 0; u < 6; ++u)
          *(unsigned*)(Kb2 + (size_t)rg * 32 + 20 + 2 * u) = 0u;
      } else if (part == 1) {
#pragma unroll
        for (int u = 0; u < 6; ++u)
          *(unsigned*)(Qb2 + (size_t)rg * 32 + 20 + 2 * u) = 0u;
      }
    }
  } else {
    // ---- fused dense1 partial over this block's 64 rows ----
    __syncthreads();                     // normalized ox visible to all
    float acc[10];
#pragma unroll
    for (int j = 0; j < 10; ++j) acc[j] = 0.f;
    const int base = q0 * 20;
    if (tid < 256) {
#pragma unroll
      for (int k = 0; k < 5; ++k) {
        const int il = tid + 256 * k;
        const float xv = ox[il];
#pragma unroll
        for (int j = 0; j < 10; ++j)
          acc[j] += xv * W1T[(size_t)j * 20480 + base + il];  // lane-coalesced
      }
    }
    // wave butterfly reduce (tid>=256 contribute zeros)
#pragma unroll
    for (int off = 1; off < 64; off <<= 1) {
#pragma unroll
      for (int j = 0; j < 10; ++j) acc[j] += __shfl_xor(acc[j], off, 64);
    }
    if (tid < 256 && lane == 0) {
#pragma unroll
      for (int j = 0; j < 10; ++j) red2[w * 10 + j] = acc[j];
    }
    __syncthreads();
    if (tid < 10) {
      float s2 = red2[tid] + red2[10 + tid] + red2[20 + tid] + red2[30 + tid];
      part2[((b << 4) + strip) * 10 + tid] = s2;
    }
  }
}

// ---------------- dense head: combine strips + dense2/3 ----------------
__global__ __launch_bounds__(64) void dense_final(
    const float* __restrict__ part2,   // [64,16,10], strip-ordered
    const float* __restrict__ B1,
    const float* __restrict__ W2, const float* __restrict__ B2,
    const float* __restrict__ W3, const float* __restrict__ B3,
    float* __restrict__ out) {
  const int b = blockIdx.x;
  __shared__ float y1[10], y2[10];
  if (threadIdx.x < 10) {
    int j = threadIdx.x;
    float s = 0.f;
#pragma unroll
    for (int st = 0; st < 16; ++st) s += part2[((b << 4) + st) * 10 + j];
    y1[j] = s + B1[j];
  }
  __syncthreads();
  if (threadIdx.x < 10) {
    int j = threadIdx.x;
    float s = B2[j];
#pragma unroll
    for (int i = 0; i < 10; ++i) s += y1[i] * W2[i * 10 + j];
    y2[j] = s;
  }
  __syncthreads();
  if (threadIdx.x < 10) {
    int j = threadIdx.x;
    float s = B3[j];
#pragma unroll
    for (int i = 0; i < 10; ++i) s += y2[i] * W3[i * 10 + j];
    out[b * 10 + j] = s;
  }
}

extern "C" void kernel_launch(void* const* d_in, const int* in_sizes, int n_in,
                              void* d_out, int out_size, void* d_ws, size_t ws_size,
                              hipStream_t stream) {
  const int*   inp = (const int*)d_in[0];
  const float* cw1 = (const float*)d_in[1];
  const float* cb1 = (const float*)d_in[2];
  const float* cw2 = (const float*)d_in[3];
  const float* cb2 = (const float*)d_in[4];
  const float* cw3 = (const float*)d_in[5];
  const float* cb3 = (const float*)d_in[6];
  const float* a1K = (const float*)d_in[7];
  const float* a1Q = (const float*)d_in[8];
  const float* a1V = (const float*)d_in[9];
  const float* a2K = (const float*)d_in[10];
  const float* a2Q = (const float*)d_in[11];
  const float* a2V = (const float*)d_in[12];
  const float* a3K = (const float*)d_in[13];
  const float* a3Q = (const float*)d_in[14];
  const float* a3V = (const float*)d_in[15];
  const float* dw1 = (const float*)d_in[16];
  const float* db1 = (const float*)d_in[17];
  const float* dw2 = (const float*)d_in[18];
  const float* db2 = (const float*)d_in[19];
  const float* dw3 = (const float*)d_in[20];
  const float* db3 = (const float*)d_in[21];
  float* outp = (float*)d_out;

  // workspace layout (float units) — R25 offsets (c2 region now unused)
  float* wsf = (float*)d_ws;
  ushort_t* qbA  = (ushort_t*)(wsf);            // [65536][32] bf16  [0 .. 1,048,576)
  ushort_t* kbA  = (ushort_t*)(wsf + 1048576);  //                   [1,048,576 .. 2,097,152)
  ushort_t* vfA  = (ushort_t*)(wsf + 2097152);  // Vf[64][64][20][16] (655,360 f)
  float*    part2= wsf + 4456448;               // [64,16,10]
  float*    w1t  = wsf + 4466688;               // [10,20480]        ends 4,671,488
  ushort_t* qbB  = (ushort_t*)(wsf + 4671488);  // ends 5,195,776
  ushort_t* kbB  = (ushort_t*)(wsf + 5712384);
  ushort_t* vfB  = (ushort_t*)(wsf + 6760960);

  conv_fused_kernel<<<256, 256, 0, stream>>>(
      inp, cw1, cb1, cw2, cb2, cw3, cb3, a1K, a1Q, a1V, qbA, kbA, vfA,
      dw1, w1t);
  // attn1: reads A, fused proj(layer2) -> B
  attn_kernel<true><<<1024, 512, 0, stream>>>(
      qbA, kbA, vfA, a2K, a2Q, a2V, qbB, kbB, vfB, nullptr, nullptr);
  // attn2: reads B, fused proj(layer3) -> A
  attn_kernel<true><<<1024, 512, 0, stream>>>(
      qbB, kbB, vfB, a3K, a3Q, a3V, qbA, kbA, vfA, nullptr, nullptr);
  // attn3: reads A, fused dense1 partial -> part2
  attn_kernel<false><<<1024, 512, 0, stream>>>(
      qbA, kbA, vfA, nullptr, nullptr, nullptr, nullptr, nullptr, nullptr,
      w1t, part2);

  dense_final<<<64, 64, 0, stream>>>(part2, db1, dw2, db2, dw3, db3, outp);
}

// Round 11
// 323.908 us; speedup vs baseline: 1.1210x; 1.1210x over previous
//
#include <hip/hip_runtime.h>
#include <hip/hip_bf16.h>

// Model: one_hot -> 3x Conv2D(5,(4,4),(1,2),SAME) -> [B,S=1024,D=20]
//        -> 3x causal self-attention -> flatten -> 3x Dense(10)
// B=64, L=8192, S=1024, D=20.
// R23 (198.5) / R25 (199.2): the plateau. R24/R27/R28/R29 all regressed
//      (occupancy steps, wave overhead, VGPR blowup); R26 null.
// R29 (363us): conv fusion -> VGPR 256, 166MB fetch. REVERTED to R25.
// R30: R25 verbatim + dense_final FOLDED into attn3 (last-block-per-b):
//      each (b,strip) block writes part2, __threadfence + device-scope
//      atomicAdd(cnt[b]); the 16th block re-fences and computes dense
//      bias+dense2+dense3 for its b (same summation order as dense_final
//      -> bit-identical). cnt zeroed in conv12's tail (stream-ordered,
//      re-zeroed each iteration). 5 launches instead of 6.

#define B_ 64
#define L_ 8192
#define S_ 1024
#define D_ 20

typedef unsigned short ushort_t;
typedef __attribute__((ext_vector_type(8))) short short8_t;  // 8 bf16 (4 VGPRs)
typedef __attribute__((ext_vector_type(4))) short short4_t;  // 4 bf16 (2 VGPRs)
typedef __attribute__((ext_vector_type(4))) float f32x4_t;   // MFMA C/D

__device__ __forceinline__ ushort_t f2bf(float f) {          // RNE fp32->bf16
  unsigned u = __float_as_uint(f);
  return (ushort_t)((u + 0x7fffu + ((u >> 16) & 1u)) >> 16);
}
__device__ __forceinline__ float bf2f(ushort_t h) {
  return __uint_as_float(((unsigned)h) << 16);
}

// ---------------- fused conv1+conv2 (+ W1 transpose + cnt-zero tail) ------
__global__ __launch_bounds__(256) void conv12_kernel(
    const int* __restrict__ inp,
    const float* __restrict__ W1c, const float* __restrict__ B1c,
    const float* __restrict__ W2c, const float* __restrict__ B2c,
    float* __restrict__ out,                      // c2 [B,4,2048,5]
    const float* __restrict__ W1d,                // dense W1 [20480,10]
    float* __restrict__ W1T,                      // [10,20480]
    unsigned* __restrict__ cnt) {                 // [64] attn3 block counters
  __shared__ float w1s[80], b1s[5], w2s[400], b2s[5];
  for (int j = threadIdx.x; j < 400; j += 256) w2s[j] = W2c[j];
  if (threadIdx.x < 80)      w1s[threadIdx.x]      = W1c[threadIdx.x];
  else if (threadIdx.x < 85) b1s[threadIdx.x - 80] = B1c[threadIdx.x - 80];
  else if (threadIdx.x < 90) b2s[threadIdx.x - 85] = B2c[threadIdx.x - 85];
  __syncthreads();
  const int idx = blockIdx.x * 256 + threadIdx.x;  // 131072 total
  const int b  = idx >> 11;
  const int wo = idx & 2047;
  const int* ib = inp + (size_t)b * L_;
  int iv[10];
#pragma unroll
  for (int t = 0; t < 10; ++t) {
    int g = 4 * wo - 3 + t;
    iv[t] = (g >= 0 && g < L_) ? ib[g] : -100;   // sentinel: no kh matches
  }
  float val[4][4][5];                            // [hi][pos][ci]
#pragma unroll
  for (int pos = 0; pos < 4; ++pos) {
    const int w1 = 2 * wo - 1 + pos;
    const bool okp = (w1 >= 0 && w1 < 4096);     // conv2 SAME padding -> 0
#pragma unroll
    for (int hi = 0; hi < 4; ++hi)
#pragma unroll
      for (int ci = 0; ci < 5; ++ci) val[hi][pos][ci] = okp ? b1s[ci] : 0.f;
    if (okp) {
#pragma unroll
      for (int kw = 0; kw < 4; ++kw) {
        const int gw = 2 * w1 - 1 + kw;
        if (gw >= 0 && gw < L_) {
          const int v = iv[2 * pos + kw];
#pragma unroll
          for (int hi = 0; hi < 4; ++hi) {
            const int kh = v - hi + 1;
            if (kh >= 0 && kh < 4) {
#pragma unroll
              for (int ci = 0; ci < 5; ++ci)
                val[hi][pos][ci] += w1s[(kh * 4 + kw) * 5 + ci];
            }
          }
        }
      }
    }
  }
  float acc[4][5];
#pragma unroll
  for (int h = 0; h < 4; ++h)
#pragma unroll
    for (int c = 0; c < 5; ++c) acc[h][c] = b2s[c];
#pragma unroll
  for (int kh = 0; kh < 4; ++kh)
#pragma unroll
    for (int kw = 0; kw < 4; ++kw)
#pragma unroll
      for (int ci = 0; ci < 5; ++ci) {
        const float* wp = w2s + ((kh * 4 + kw) * 5 + ci) * 5;
        float w0 = wp[0], w1v = wp[1], w2v = wp[2], w3 = wp[3], w4 = wp[4];
#pragma unroll
        for (int h = 0; h < 4; ++h) {
          int hi = h - 1 + kh;
          if (hi >= 0 && hi < 4) {
            float x = val[hi][kw][ci];
            acc[h][0] += w0 * x;  acc[h][1] += w1v * x; acc[h][2] += w2v * x;
            acc[h][3] += w3 * x;  acc[h][4] += w4 * x;
          }
        }
      }
  float* ob = out + (size_t)b * 4 * 2048 * 5;
#pragma unroll
  for (int h = 0; h < 4; ++h)
#pragma unroll
    for (int c = 0; c < 5; ++c) ob[(h * 2048 + wo) * 5 + c] = acc[h][c];
  // ---- tail: W1 transpose (grid-stride) + attn3 counter zeroing ----
  for (int j = idx; j < 204800; j += 131072) {
    int col = j / 20480, i2 = j - col * 20480;
    W1T[j] = W1d[i2 * 10 + col];
  }
  if (idx < 64) cnt[idx] = 0u;
}

// ---------------- fused conv3 + proj (layer 1) ----------------
__global__ __launch_bounds__(256) void conv3_proj_kernel(
    const float* __restrict__ in,                 // c2 [B,4,2048,5]
    const float* __restrict__ W,  const float* __restrict__ Bi,
    const float* __restrict__ Kw, const float* __restrict__ Qw,
    const float* __restrict__ Vw,
    ushort_t* __restrict__ Qb, ushort_t* __restrict__ Kb,
    ushort_t* __restrict__ Vf) {                  // Vf[b][64][20][16]
  constexpr int WIN = 2048;
  __shared__ float ws[400], bs[5];
  __shared__ float kw[400], qw[400], vw[400];
  for (int j = threadIdx.x; j < 400; j += 256) {
    ws[j] = W[j]; kw[j] = Kw[j]; qw[j] = Qw[j]; vw[j] = Vw[j];
  }
  if (threadIdx.x < 5) bs[threadIdx.x] = Bi[threadIdx.x];
  __syncthreads();
  const int r  = blockIdx.x * 256 + threadIdx.x;  // row in [0, 65536)
  const int b  = r >> 10;
  const int wo = r & 1023;
  float val[4][4][5];
#pragma unroll
  for (int hi = 0; hi < 4; ++hi) {
    const float* ir = in + ((size_t)b * 4 + hi) * WIN * 5;
#pragma unroll
    for (int kwp = 0; kwp < 4; ++kwp) {
      int wi = 2 * wo - 1 + kwp;
      bool ok = (wi >= 0 && wi < WIN);
#pragma unroll
      for (int ci = 0; ci < 5; ++ci) val[hi][kwp][ci] = ok ? ir[wi * 5 + ci] : 0.f;
    }
  }
  float acc[4][5];
#pragma unroll
  for (int h = 0; h < 4; ++h)
#pragma unroll
    for (int c = 0; c < 5; ++c) acc[h][c] = bs[c];
#pragma unroll
  for (int kh = 0; kh < 4; ++kh)
#pragma unroll
    for (int kwp = 0; kwp < 4; ++kwp)
#pragma unroll
      for (int ci = 0; ci < 5; ++ci) {
        const float* wp = ws + ((kh * 4 + kwp) * 5 + ci) * 5;
        float w0 = wp[0], w1 = wp[1], w2 = wp[2], w3 = wp[3], w4 = wp[4];
#pragma unroll
        for (int h = 0; h < 4; ++h) {
          int hi = h - 1 + kh;
          if (hi >= 0 && hi < 4) {
            float x = val[hi][kwp][ci];
            acc[h][0] += w0 * x; acc[h][1] += w1 * x; acc[h][2] += w2 * x;
            acc[h][3] += w3 * x; acc[h][4] += w4 * x;
          }
        }
      }
  float x[D_];
#pragma unroll
  for (int h = 0; h < 4; ++h)
#pragma unroll
    for (int c = 0; c < 5; ++c) x[h * 5 + c] = acc[h][c];
  float q[D_], k[D_], v[D_];
#pragma unroll
  for (int j = 0; j < D_; ++j) { q[j] = 0.f; k[j] = 0.f; v[j] = 0.f; }
#pragma unroll
  for (int i = 0; i < D_; ++i) {
#pragma unroll
    for (int j = 0; j < D_; ++j) {
      q[j] += x[i] * qw[i * D_ + j];
      k[j] += x[i] * kw[i * D_ + j];
      v[j] += x[i] * vw[i * D_ + j];
    }
  }
  const float sc = 0.22360679774997896f;  // 1/sqrt(20)
  ushort_t qt[32], kt[32];
#pragma unroll
  for (int j = 0; j < D_; ++j) { qt[j] = f2bf(q[j] * sc); kt[j] = f2bf(k[j]); }
#pragma unroll
  for (int j = D_; j < 32; ++j) { qt[j] = 0; kt[j] = 0; }
  int4* qd = (int4*)(Qb + (size_t)r * 32);
  int4* kd = (int4*)(Kb + (size_t)r * 32);
#pragma unroll
  for (int j = 0; j < 4; ++j) {
    qd[j] = *(const int4*)(qt + 8 * j);
    kd[j] = *(const int4*)(kt + 8 * j);
  }
  // fragment-major V: Vf[b][wo>>4][d][wo&15]
  ushort_t* vbase = Vf + ((size_t)b * 64 + (wo >> 4)) * 320 + (wo & 15);
#pragma unroll
  for (int d = 0; d < D_; ++d) vbase[d * 16] = f2bf(v[d]);
}

// ---------------- causal attention: 8 waves = (q-subtile, t-half) ---------
// S^T = mfma_16x16x32(Kfrag, Qfrag): lane (quad,n): S^T[t=quad*4+r][q=n].
// P^T register layout IS the B-operand of mfma_16x16x16; PV from registers.
// K and Vf both read DIRECT from global, fully coalesced; L2-hot per b.
// (R25 verbatim main loop.)
// FUSE=true : epilogue projects O rows -> next layer's Qb2/Kb2/Vf2.
// FUSE=false: epilogue computes dense1 partial -> part2[b][strip][10];
//             the LAST block per b (device-scope atomic) computes the
//             dense head (bias + dense2 + dense3) -> outp.
template <bool FUSE>
__global__ __launch_bounds__(512, 8) void attn_kernel(
    const ushort_t* __restrict__ Qb, const ushort_t* __restrict__ Kb,
    const ushort_t* __restrict__ Vf,
    const float* __restrict__ Kw2, const float* __restrict__ Qw2,
    const float* __restrict__ Vw2,
    ushort_t* __restrict__ Qb2, ushort_t* __restrict__ Kb2,
    ushort_t* __restrict__ Vf2,
    const float* __restrict__ W1T,   // !FUSE: [10,20480]
    float* __restrict__ part2,       // !FUSE: [64,16,10]
    const float* __restrict__ B1d, const float* __restrict__ W2d,
    const float* __restrict__ B2d, const float* __restrict__ W3d,
    const float* __restrict__ B3d, float* __restrict__ outp,
    unsigned* __restrict__ cnt) {    // !FUSE: [64]
  __shared__ float ox[1280];                  // merged O rows [4 subtiles x 320]
  __shared__ float pw_s[FUSE ? 1200 : 4];     // proj weights (FUSE)
  __shared__ float mrgL[64];                  // half1 l partials [sub][n]
  __shared__ float red2[40];                  // !FUSE per-wave dense sums
  __shared__ float y1[16], y2[16];            // !FUSE dense head temporaries
  __shared__ unsigned done_s;
  const int blk   = blockIdx.x;
  const int b     = blk & 63;                 // blk%8==b%8 -> XCD locality
  const int raw   = blk >> 6;                 // 0..15
  const int rr4   = raw & 3, k4 = raw >> 2;
  const int strip = (k4 == 0) ? rr4 : (k4 == 1) ? 7 - rr4
                  : (k4 == 2) ? 8 + rr4 : 15 - rr4;  // per-CU sum const
  const int q0    = strip * 64;
  const int nt    = q0 + 64;
  const int tid   = threadIdx.x;
  const int w     = tid >> 6;                 // wave 0..7
  const int sub   = w & 3;                    // q-subtile
  const int half  = w >> 2;                   // t-half
  const int lane  = tid & 63;
  const int n     = lane & 15;
  const int quad  = lane >> 4;
  const int qbase = q0 + 16 * sub;
  const int qg    = qbase + n;                // this lane's q column
  if (FUSE) {
    for (int i = tid; i < 1200; i += 512) {
      int m = i / 400, oo = i - m * 400;
      pw_s[i] = (m == 0) ? Kw2[oo] : (m == 1) ? Qw2[oo] : Vw2[oo];
    }
  }
  const ushort_t* KbB  = Kb + (size_t)b * 1024 * 32;
  const ushort_t* VfB  = Vf + (size_t)b * 20480;       // [64][20][16]
  const ushort_t* vloB = VfB + n * 16 + quad * 4;
  const ushort_t* vhiB = VfB + (16 + (n & 3)) * 16 + quad * 4;
  short8_t qfrag = *(const short8_t*)(Qb + ((size_t)(b * 1024 + qbase + n)) * 32 + quad * 8);
  f32x4_t oA = {0.f, 0.f, 0.f, 0.f};          // O^T[d=quad*4+r][q=n]
  f32x4_t oB = {0.f, 0.f, 0.f, 0.f};          // O^T[d=16+quad*4+r][q=n] (quad0)
  const f32x4_t zero = {0.f, 0.f, 0.f, 0.f};
  float lsum = 0.f;
  const int nt2 = nt >> 1;
  const int tlo = half ? nt2 : 0;
  int thi = half ? nt : nt2;
  if (thi > qbase + 16) thi = qbase + 16;     // wave-uniform: skip all-masked
  for (int t0 = tlo; t0 < thi; t0 += 32) {
    short8_t kf0 = *(const short8_t*)(KbB + (size_t)(t0 + n) * 32 + quad * 8);
    short8_t kf1 = *(const short8_t*)(KbB + (size_t)(t0 + 16 + n) * 32 + quad * 8);
#pragma unroll
    for (int c = 0; c < 2; ++c) {
      const int tg = t0 + c * 16 + quad * 4;  // global t of r=0
      f32x4_t s = __builtin_amdgcn_mfma_f32_16x16x32_bf16(c ? kf1 : kf0, qfrag,
                                                          zero, 0, 0, 0);
      ushort_t pk4[4];
#pragma unroll
      for (int r = 0; r < 4; ++r) {
        float p = (tg + r <= qg) ? __expf(s[r]) : 0.f;
        ushort_t h = f2bf(p);
        lsum += bf2f(h);                      // consistent with bf16 P in PV
        pk4[r] = h;
      }
      short4_t pfrag = *(const short4_t*)pk4; // B16-frag: k=quad*4+j, n=q
      const int tb = (t0 >> 4) + c;           // 16-t fragment block index
      short4_t vlo = *(const short4_t*)(vloB + tb * 320);
      short4_t vhi = *(const short4_t*)(vhiB + tb * 320);
      oA = __builtin_amdgcn_mfma_f32_16x16x16bf16_1k(vlo, pfrag, oA, 0, 0, 0);
      oB = __builtin_amdgcn_mfma_f32_16x16x16bf16_1k(vhi, pfrag, oB, 0, 0, 0);
    }
  }
  // l[q=n]: reduce partial sums across the 4 quads
  float l = lsum;
  l += __shfl_xor(l, 16, 64);
  l += __shfl_xor(l, 32, 64);
  float* oxw = ox + sub * 320;
  // ---- merge halves: half1 writes partials (ox layout), half0 adds ----
  if (half) {
#pragma unroll
    for (int r = 0; r < 4; ++r) oxw[n * 20 + quad * 4 + r] = oA[r];
    if (quad == 0) {
#pragma unroll
      for (int r = 0; r < 4; ++r) oxw[n * 20 + 16 + r] = oB[r];
      mrgL[sub * 16 + n] = l;
    }
  }
  __syncthreads();
  if (!half) {
#pragma unroll
    for (int r = 0; r < 4; ++r) oA[r] += oxw[n * 20 + quad * 4 + r];
    if (quad == 0) {
#pragma unroll
      for (int r = 0; r < 4; ++r) oB[r] += oxw[n * 20 + 16 + r];
    }
    l += mrgL[sub * 16 + n];                  // broadcast read per n
    const float inv = 1.f / l;
    // overwrite own region with normalized O
#pragma unroll
    for (int r = 0; r < 4; ++r) oxw[n * 20 + quad * 4 + r] = oA[r] * inv;
    if (quad == 0) {
#pragma unroll
      for (int r = 0; r < 4; ++r) oxw[n * 20 + 16 + r] = oB[r] * inv;
    }
  }
  if (FUSE) {
    if (!half) {
      __asm__ volatile("s_waitcnt lgkmcnt(0)" ::: "memory");  // wave LDS RAW
      const int row  = lane >> 2;     // 0..15
      const int part = lane & 3;      // cols 5*part .. 5*part+4
      float x[D_];
#pragma unroll
      for (int i = 0; i < D_; ++i) x[i] = oxw[row * 20 + i];
      float qv[5], kv[5], vv[5];
#pragma unroll
      for (int jj = 0; jj < 5; ++jj) { qv[jj] = 0.f; kv[jj] = 0.f; vv[jj] = 0.f; }
#pragma unroll
      for (int i = 0; i < D_; ++i) {
        const float xi = x[i];
#pragma unroll
        for (int jj = 0; jj < 5; ++jj) {
          const int j = 5 * part + jj;
          kv[jj] += xi * pw_s[i * 20 + j];          // K block
          qv[jj] += xi * pw_s[400 + i * 20 + j];    // Q block
          vv[jj] += xi * pw_s[800 + i * 20 + j];    // V block
        }
      }
      const float sc = 0.22360679774997896f;
      const int rg = b * 1024 + qbase + row;
      const int s  = rg & 1023;
#pragma unroll
      for (int jj = 0; jj < 5; ++jj) {
        const int j = 5 * part + jj;
        Kb2[(size_t)rg * 32 + j] = f2bf(kv[jj]);
        Qb2[(size_t)rg * 32 + j] = f2bf(qv[jj] * sc);
        Vf2[(size_t)b * 20480 + (size_t)(s >> 4) * 320 + j * 16 + (s & 15)] =
            f2bf(vv[jj]);
      }
      if (part == 0) {
#pragma unroll
        for (int u = 0; u < 6; ++u)
          *(unsigned*)(Kb2 + (size_t)rg * 32 + 20 + 2 * u) = 0u;
      } else if (part == 1) {
#pragma unroll
        for (int u = 0; u < 6; ++u)
          *(unsigned*)(Qb2 + (size_t)rg * 32 + 20 + 2 * u) = 0u;
      }
    }
  } else {
    // ---- fused dense1 partial over this block's 64 rows ----
    __syncthreads();                     // normalized ox visible to all
    float acc[10];
#pragma unroll
    for (int j = 0; j < 10; ++j) acc[j] = 0.f;
    const int base = q0 * 20;
    if (tid < 256) {
#pragma unroll
      for (int k = 0; k < 5; ++k) {
        const int il = tid + 256 * k;
        const float xv = ox[il];
#pragma unroll
        for (int j = 0; j < 10; ++j)
          acc[j] += xv * W1T[(size_t)j * 20480 + base + il];  // lane-coalesced
      }
    }
    // wave butterfly reduce (tid>=256 contribute zeros)
#pragma unroll
    for (int off = 1; off < 64; off <<= 1) {
#pragma unroll
      for (int j = 0; j < 10; ++j) acc[j] += __shfl_xor(acc[j], off, 64);
    }
    if (tid < 256 && lane == 0) {
#pragma unroll
      for (int j = 0; j < 10; ++j) red2[w * 10 + j] = acc[j];
    }
    __syncthreads();
    if (tid < 10) {
      float s2 = red2[tid] + red2[10 + tid] + red2[20 + tid] + red2[30 + tid];
      part2[((b << 4) + strip) * 10 + tid] = s2;
    }
    // ---- last-block-per-b: fold the dense head in (replaces dense_final)
    __threadfence();                     // part2 stores visible device-wide
    __syncthreads();
    if (tid == 0) done_s = atomicAdd(&cnt[b], 1u);
    __syncthreads();
    if (done_s == 15u) {                 // this is the 16th (last) block for b
      __threadfence();                   // acquire: see other blocks' part2
      if (tid < 10) {
        int j = tid;
        float s = 0.f;
#pragma unroll
        for (int st = 0; st < 16; ++st) s += part2[((b << 4) + st) * 10 + j];
        y1[j] = s + B1d[j];
      }
      __syncthreads();
      if (tid < 10) {
        int j = tid;
        float s = B2d[j];
#pragma unroll
        for (int i = 0; i < 10; ++i) s += y1[i] * W2d[i * 10 + j];
        y2[j] = s;
      }
      __syncthreads();
      if (tid < 10) {
        int j = tid;
        float s = B3d[j];
#pragma unroll
        for (int i = 0; i < 10; ++i) s += y2[i] * W3d[i * 10 + j];
        outp[b * 10 + j] = s;
      }
    }
  }
}

extern "C" void kernel_launch(void* const* d_in, const int* in_sizes, int n_in,
                              void* d_out, int out_size, void* d_ws, size_t ws_size,
                              hipStream_t stream) {
  const int*   inp = (const int*)d_in[0];
  const float* cw1 = (const float*)d_in[1];
  const float* cb1 = (const float*)d_in[2];
  const float* cw2 = (const float*)d_in[3];
  const float* cb2 = (const float*)d_in[4];
  const float* cw3 = (const float*)d_in[5];
  const float* cb3 = (const float*)d_in[6];
  const float* a1K = (const float*)d_in[7];
  const float* a1Q = (const float*)d_in[8];
  const float* a1V = (const float*)d_in[9];
  const float* a2K = (const float*)d_in[10];
  const float* a2Q = (const float*)d_in[11];
  const float* a2V = (const float*)d_in[12];
  const float* a3K = (const float*)d_in[13];
  const float* a3Q = (const float*)d_in[14];
  const float* a3V = (const float*)d_in[15];
  const float* dw1 = (const float*)d_in[16];
  const float* db1 = (const float*)d_in[17];
  const float* dw2 = (const float*)d_in[18];
  const float* db2 = (const float*)d_in[19];
  const float* dw3 = (const float*)d_in[20];
  const float* db3 = (const float*)d_in[21];
  float* outp = (float*)d_out;

  // workspace layout (float units) — R25 offsets + cnt in the free gap
  float* wsf = (float*)d_ws;
  ushort_t* qbA  = (ushort_t*)(wsf);            // [65536][32] bf16  [0 .. 1,048,576)
  ushort_t* kbA  = (ushort_t*)(wsf + 1048576);  //                   [1,048,576 .. 2,097,152)
  ushort_t* vfA  = (ushort_t*)(wsf + 2097152);  // Vf[64][64][20][16] (655,360 f)
  unsigned* cnt  = (unsigned*)(wsf + 4000000);  // [64] (free region)
  float*    part2= wsf + 4456448;               // [64,16,10]
  float*    w1t  = wsf + 4466688;               // [10,20480]        ends 4,671,488
  ushort_t* qbB  = (ushort_t*)(wsf + 4671488);  // ends 5,195,776
  ushort_t* kbB  = (ushort_t*)(wsf + 5712384);  // B-buffers overlap dead c2 region
  ushort_t* vfB  = (ushort_t*)(wsf + 6760960);  //   (c2 consumed before attn1 writes B)
  float*    c2   = wsf + 5242880;               // [B,4,2048,5]      [5,242,880 .. 7,864,320)

  conv12_kernel<<<512, 256, 0, stream>>>(inp, cw1, cb1, cw2, cb2, c2, dw1,
                                         w1t, cnt);

  conv3_proj_kernel<<<256, 256, 0, stream>>>(c2, cw3, cb3, a1K, a1Q, a1V,
                                             qbA, kbA, vfA);
  // attn1: reads A, fused proj(layer2) -> B
  attn_kernel<true><<<1024, 512, 0, stream>>>(
      qbA, kbA, vfA, a2K, a2Q, a2V, qbB, kbB, vfB, nullptr, nullptr,
      nullptr, nullptr, nullptr, nullptr, nullptr, nullptr, nullptr);
  // attn2: reads B, fused proj(layer3) -> A
  attn_kernel<true><<<1024, 512, 0, stream>>>(
      qbB, kbB, vfB, a3K, a3Q, a3V, qbA, kbA, vfA, nullptr, nullptr,
      nullptr, nullptr, nullptr, nullptr, nullptr, nullptr, nullptr);
  // attn3: reads A, fused dense1 partial + last-block dense head -> outp
  attn_kernel<false><<<1024, 512, 0, stream>>>(
      qbA, kbA, vfA, nullptr, nullptr, nullptr, nullptr, nullptr, nullptr,
      w1t, part2, db1, dw2, db2, dw3, db3, outp, cnt);
}

// Round 12
// 195.913 us; speedup vs baseline: 1.8533x; 1.6533x over previous
//
#include <hip/hip_runtime.h>
#include <hip/hip_bf16.h>

// Model: one_hot -> 3x Conv2D(5,(4,4),(1,2),SAME) -> [B,S=1024,D=20]
//        -> 3x causal self-attention -> flatten -> 3x Dense(10)
// B=64, L=8192, S=1024, D=20.
// R23 (198.5us, session best): attn 512-thr, 8 waves=(q-subtile,t-half),
//      V^T staged once, zero main-loop barriers, K direct-global, masked-
//      group skip. R24-R30: all null or regressed (occupancy steps, wave
//      overhead, VGPR blowup, threadfence serialization). REVERTED to R23.
// R31: dense head is AFFINE (no activations) -> composes:
//      out = X@(W1@W2@W3) + (B1@W2@W3 + B2@W3 + B3).
//      conv12's W1-transpose tail now emits the COMPOSED W1T_c[10][20480]
//      (+~170 FMA/thread) and initializes out[640] = composed bias
//      (stream-ordered before attn3; re-done each iteration).
//      attn3's epilogue atomicAdds its 10 per-block partials into out
//      (16 blocks/b, fp32 device-scope, no fence/counter). dense_final
//      DELETED -> 5 launches. Numerics: same-accuracy different rounding
//      path + atomic order -> absmax ~1e-5 expected.

#define B_ 64
#define L_ 8192
#define S_ 1024
#define D_ 20

typedef unsigned short ushort_t;
typedef __attribute__((ext_vector_type(8))) short short8_t;  // 8 bf16 (4 VGPRs)
typedef __attribute__((ext_vector_type(4))) short short4_t;  // 4 bf16 (2 VGPRs)
typedef __attribute__((ext_vector_type(4))) float f32x4_t;   // MFMA C/D

__device__ __forceinline__ ushort_t f2bf(float f) {          // RNE fp32->bf16
  unsigned u = __float_as_uint(f);
  return (ushort_t)((u + 0x7fffu + ((u >> 16) & 1u)) >> 16);
}
__device__ __forceinline__ float bf2f(ushort_t h) {
  return __uint_as_float(((unsigned)h) << 16);
}

// ------- fused conv1+conv2 (+ composed-W1T tail + out bias init) ---------
__global__ __launch_bounds__(256) void conv12_kernel(
    const int* __restrict__ inp,
    const float* __restrict__ W1c, const float* __restrict__ B1c,
    const float* __restrict__ W2c, const float* __restrict__ B2c,
    float* __restrict__ out,                      // c2 [B,4,2048,5]
    const float* __restrict__ W1d,                // dense W1 [20480,10]
    float* __restrict__ W1T,                      // [10,20480] COMPOSED
    const float* __restrict__ B1d, const float* __restrict__ W2d,
    const float* __restrict__ B2d, const float* __restrict__ W3d,
    const float* __restrict__ B3d,
    float* __restrict__ outp) {                   // [64,10] bias-initialized
  __shared__ float w1s[80], b1s[5], w2s[400], b2s[5];
  for (int j = threadIdx.x; j < 400; j += 256) w2s[j] = W2c[j];
  if (threadIdx.x < 80)      w1s[threadIdx.x]      = W1c[threadIdx.x];
  else if (threadIdx.x < 85) b1s[threadIdx.x - 80] = B1c[threadIdx.x - 80];
  else if (threadIdx.x < 90) b2s[threadIdx.x - 85] = B2c[threadIdx.x - 85];
  __syncthreads();
  const int idx = blockIdx.x * 256 + threadIdx.x;  // 131072 total
  const int b  = idx >> 11;
  const int wo = idx & 2047;
  const int* ib = inp + (size_t)b * L_;
  int iv[10];
#pragma unroll
  for (int t = 0; t < 10; ++t) {
    int g = 4 * wo - 3 + t;
    iv[t] = (g >= 0 && g < L_) ? ib[g] : -100;   // sentinel: no kh matches
  }
  float val[4][4][5];                            // [hi][pos][ci]
#pragma unroll
  for (int pos = 0; pos < 4; ++pos) {
    const int w1 = 2 * wo - 1 + pos;
    const bool okp = (w1 >= 0 && w1 < 4096);     // conv2 SAME padding -> 0
#pragma unroll
    for (int hi = 0; hi < 4; ++hi)
#pragma unroll
      for (int ci = 0; ci < 5; ++ci) val[hi][pos][ci] = okp ? b1s[ci] : 0.f;
    if (okp) {
#pragma unroll
      for (int kw = 0; kw < 4; ++kw) {
        const int gw = 2 * w1 - 1 + kw;
        if (gw >= 0 && gw < L_) {
          const int v = iv[2 * pos + kw];
#pragma unroll
          for (int hi = 0; hi < 4; ++hi) {
            const int kh = v - hi + 1;
            if (kh >= 0 && kh < 4) {
#pragma unroll
              for (int ci = 0; ci < 5; ++ci)
                val[hi][pos][ci] += w1s[(kh * 4 + kw) * 5 + ci];
            }
          }
        }
      }
    }
  }
  float acc[4][5];
#pragma unroll
  for (int h = 0; h < 4; ++h)
#pragma unroll
    for (int c = 0; c < 5; ++c) acc[h][c] = b2s[c];
#pragma unroll
  for (int kh = 0; kh < 4; ++kh)
#pragma unroll
    for (int kw = 0; kw < 4; ++kw)
#pragma unroll
      for (int ci = 0; ci < 5; ++ci) {
        const float* wp = w2s + ((kh * 4 + kw) * 5 + ci) * 5;
        float w0 = wp[0], w1v = wp[1], w2v = wp[2], w3 = wp[3], w4 = wp[4];
#pragma unroll
        for (int h = 0; h < 4; ++h) {
          int hi = h - 1 + kh;
          if (hi >= 0 && hi < 4) {
            float x = val[hi][kw][ci];
            acc[h][0] += w0 * x;  acc[h][1] += w1v * x; acc[h][2] += w2v * x;
            acc[h][3] += w3 * x;  acc[h][4] += w4 * x;
          }
        }
      }
  float* ob = out + (size_t)b * 4 * 2048 * 5;
#pragma unroll
  for (int h = 0; h < 4; ++h)
#pragma unroll
    for (int c = 0; c < 5; ++c) ob[(h * 2048 + wo) * 5 + c] = acc[h][c];
  // ---- tail: COMPOSED W1T_c[col][i2] = sum_k W1[i2,k] * (W2@W3)[k,col] ----
  for (int j = idx; j < 204800; j += 131072) {
    const int col = j / 20480, i2 = j - col * 20480;
    float w23[10];
#pragma unroll
    for (int k2 = 0; k2 < 10; ++k2) {
      float s = 0.f;
#pragma unroll
      for (int m = 0; m < 10; ++m) s += W2d[k2 * 10 + m] * W3d[m * 10 + col];
      w23[k2] = s;
    }
    float s = 0.f;
#pragma unroll
    for (int k2 = 0; k2 < 10; ++k2) s += W1d[i2 * 10 + k2] * w23[k2];
    W1T[j] = s;
  }
  // ---- out init: composed bias Bc = B1@(W2@W3) + B2@W3 + B3 ----
  if (idx < 640) {
    const int col = idx - (idx / 10) * 10;
    float bc = B3d[col];
#pragma unroll
    for (int m = 0; m < 10; ++m) bc += B2d[m] * W3d[m * 10 + col];
#pragma unroll
    for (int k2 = 0; k2 < 10; ++k2) {
      float w23 = 0.f;
#pragma unroll
      for (int m = 0; m < 10; ++m) w23 += W2d[k2 * 10 + m] * W3d[m * 10 + col];
      bc += B1d[k2] * w23;
    }
    outp[idx] = bc;
  }
}

// ---------------- fused conv3 + proj (layer 1) ----------------
__global__ __launch_bounds__(256) void conv3_proj_kernel(
    const float* __restrict__ in,                 // c2 [B,4,2048,5]
    const float* __restrict__ W,  const float* __restrict__ Bi,
    const float* __restrict__ Kw, const float* __restrict__ Qw,
    const float* __restrict__ Vw,
    ushort_t* __restrict__ Qb, ushort_t* __restrict__ Kb,
    ushort_t* __restrict__ Vt) {
  constexpr int WIN = 2048;
  __shared__ float ws[400], bs[5];
  __shared__ float kw[400], qw[400], vw[400];
  for (int j = threadIdx.x; j < 400; j += 256) {
    ws[j] = W[j]; kw[j] = Kw[j]; qw[j] = Qw[j]; vw[j] = Vw[j];
  }
  if (threadIdx.x < 5) bs[threadIdx.x] = Bi[threadIdx.x];
  __syncthreads();
  const int r  = blockIdx.x * 256 + threadIdx.x;  // row in [0, 65536)
  const int b  = r >> 10;
  const int wo = r & 1023;
  float val[4][4][5];
#pragma unroll
  for (int hi = 0; hi < 4; ++hi) {
    const float* ir = in + ((size_t)b * 4 + hi) * WIN * 5;
#pragma unroll
    for (int kwp = 0; kwp < 4; ++kwp) {
      int wi = 2 * wo - 1 + kwp;
      bool ok = (wi >= 0 && wi < WIN);
#pragma unroll
      for (int ci = 0; ci < 5; ++ci) val[hi][kwp][ci] = ok ? ir[wi * 5 + ci] : 0.f;
    }
  }
  float acc[4][5];
#pragma unroll
  for (int h = 0; h < 4; ++h)
#pragma unroll
    for (int c = 0; c < 5; ++c) acc[h][c] = bs[c];
#pragma unroll
  for (int kh = 0; kh < 4; ++kh)
#pragma unroll
    for (int kwp = 0; kwp < 4; ++kwp)
#pragma unroll
      for (int ci = 0; ci < 5; ++ci) {
        const float* wp = ws + ((kh * 4 + kwp) * 5 + ci) * 5;
        float w0 = wp[0], w1 = wp[1], w2 = wp[2], w3 = wp[3], w4 = wp[4];
#pragma unroll
        for (int h = 0; h < 4; ++h) {
          int hi = h - 1 + kh;
          if (hi >= 0 && hi < 4) {
            float x = val[hi][kwp][ci];
            acc[h][0] += w0 * x; acc[h][1] += w1 * x; acc[h][2] += w2 * x;
            acc[h][3] += w3 * x; acc[h][4] += w4 * x;
          }
        }
      }
  float x[D_];
#pragma unroll
  for (int h = 0; h < 4; ++h)
#pragma unroll
    for (int c = 0; c < 5; ++c) x[h * 5 + c] = acc[h][c];
  float q[D_], k[D_], v[D_];
#pragma unroll
  for (int j = 0; j < D_; ++j) { q[j] = 0.f; k[j] = 0.f; v[j] = 0.f; }
#pragma unroll
  for (int i = 0; i < D_; ++i) {
#pragma unroll
    for (int j = 0; j < D_; ++j) {
      q[j] += x[i] * qw[i * D_ + j];
      k[j] += x[i] * kw[i * D_ + j];
      v[j] += x[i] * vw[i * D_ + j];
    }
  }
  const float sc = 0.22360679774997896f;  // 1/sqrt(20)
  ushort_t qt[32], kt[32];
#pragma unroll
  for (int j = 0; j < D_; ++j) { qt[j] = f2bf(q[j] * sc); kt[j] = f2bf(k[j]); }
#pragma unroll
  for (int j = D_; j < 32; ++j) { qt[j] = 0; kt[j] = 0; }
  int4* qd = (int4*)(Qb + (size_t)r * 32);
  int4* kd = (int4*)(Kb + (size_t)r * 32);
#pragma unroll
  for (int j = 0; j < 4; ++j) {
    qd[j] = *(const int4*)(qt + 8 * j);
    kd[j] = *(const int4*)(kt + 8 * j);
  }
  ushort_t* vbase = Vt + ((size_t)b * 32) * 1024 + wo;
#pragma unroll
  for (int d = 0; d < D_; ++d) vbase[d * 1024] = f2bf(v[d]);
}

// ---------------- causal attention: 8 waves = (q-subtile, t-half) ---------
// S^T = mfma_16x16x32(Kfrag, Qfrag): lane (quad,n): S^T[t=quad*4+r][q=n].
// P^T register layout IS the B-operand of mfma_16x16x16; PV from registers.
// V^T rows 0..19 staged ONCE (stride 1032 us); K direct from global
// (16 rows x 64B contiguous per wave instr, L1/L2-hit). Zero main-loop
// barriers. (R23 verbatim main loop.)
// FUSE=true : epilogue projects O rows -> next layer's Qb2/Kb2/Vt2.
// FUSE=false: epilogue atomicAdds composed-dense partials into outp[b][10].
template <bool FUSE>
__global__ __launch_bounds__(512, 6) void attn_kernel(
    const ushort_t* __restrict__ Qb, const ushort_t* __restrict__ Kb,
    const ushort_t* __restrict__ Vt,
    const float* __restrict__ Kw2, const float* __restrict__ Qw2,
    const float* __restrict__ Vw2,
    ushort_t* __restrict__ Qb2, ushort_t* __restrict__ Kb2,
    ushort_t* __restrict__ Vt2,
    const float* __restrict__ W1T,   // !FUSE: composed [10,20480]
    float* __restrict__ outp) {      // !FUSE: [64,10] (bias-initialized)
  constexpr int VST = 1032;                   // ushort stride (pad 8)
  __shared__ ushort_t vts[20 * VST];          // 41,280 B
  __shared__ float extraf[FUSE ? 2480 : 1280]; // FUSE: pw 1200 + ox 1280
  __shared__ float mrgL[64];                  // half1 l partials [sub][n]
  __shared__ float red2[FUSE ? 4 : 40];       // !FUSE: per-wave dense sums
  const int blk   = blockIdx.x;
  const int b     = blk & 63;                 // blk%8==b%8 -> XCD locality
  const int strip = 15 - (blk >> 6);          // heavy strips dispatch first
  const int q0    = strip * 64;
  const int nt    = q0 + 64;
  const int tid   = threadIdx.x;
  const int w     = tid >> 6;                 // wave 0..7
  const int sub   = w & 3;                    // q-subtile
  const int half  = w >> 2;                   // t-half
  const int lane  = tid & 63;
  const int n     = lane & 15;
  const int quad  = lane >> 4;
  const int qbase = q0 + 16 * sub;
  const int qg    = qbase + n;                // this lane's q column
  // ---- stage V^T rows 0..19, t < nt (once; no other barriers) ----
  const ushort_t* VtB = Vt + (size_t)b * 32 * 1024;
  const int ntc = nt >> 3;                    // 16B chunks per row
  for (int i = tid; i < 20 * ntc; i += 512) {
    int row = i / ntc, cc = i - row * ntc;
    *(int4*)(vts + row * VST + cc * 8) =
        *(const int4*)(VtB + (size_t)row * 1024 + cc * 8);
  }
  if (FUSE) {
    for (int j = tid; j < 1200; j += 512) {
      int m = j / 400, oo = j - m * 400;
      extraf[j] = (m == 0) ? Kw2[oo] : (m == 1) ? Qw2[oo] : Vw2[oo];
    }
  }
  const ushort_t* KbB = Kb + (size_t)b * 1024 * 32;
  short8_t qfrag = *(const short8_t*)(Qb + ((size_t)(b * 1024 + qbase + n)) * 32 + quad * 8);
  f32x4_t oA = {0.f, 0.f, 0.f, 0.f};          // O^T[d=quad*4+r][q=n]
  f32x4_t oB = {0.f, 0.f, 0.f, 0.f};          // O^T[d=16+quad*4+r][q=n] (quad0)
  const f32x4_t zero = {0.f, 0.f, 0.f, 0.f};
  float lsum = 0.f;
  const int nt2 = nt >> 1;
  const int tlo = half ? nt2 : 0;
  int thi = half ? nt : nt2;
  if (thi > qbase + 16) thi = qbase + 16;     // wave-uniform: skip all-masked
  __syncthreads();                            // vts (+pw) visible
  for (int t0 = tlo; t0 < thi; t0 += 32) {
    short8_t kf0 = *(const short8_t*)(KbB + (size_t)(t0 + n) * 32 + quad * 8);
    short8_t kf1 = *(const short8_t*)(KbB + (size_t)(t0 + 16 + n) * 32 + quad * 8);
#pragma unroll
    for (int c = 0; c < 2; ++c) {
      const int tg = t0 + c * 16 + quad * 4;  // global t of r=0
      f32x4_t s = __builtin_amdgcn_mfma_f32_16x16x32_bf16(c ? kf1 : kf0, qfrag,
                                                          zero, 0, 0, 0);
      ushort_t pk4[4];
#pragma unroll
      for (int r = 0; r < 4; ++r) {
        float p = (tg + r <= qg) ? __expf(s[r]) : 0.f;
        ushort_t h = f2bf(p);
        lsum += bf2f(h);                      // consistent with bf16 P in PV
        pk4[r] = h;
      }
      short4_t pfrag = *(const short4_t*)pk4; // B16-frag: k=quad*4+j, n=q
      short4_t vlo = *(const short4_t*)(vts + n * VST + t0 + c * 16 + quad * 4);
      short4_t vhi = *(const short4_t*)(vts + (16 + (n & 3)) * VST + t0 + c * 16 + quad * 4);
      oA = __builtin_amdgcn_mfma_f32_16x16x16bf16_1k(vlo, pfrag, oA, 0, 0, 0);
      oB = __builtin_amdgcn_mfma_f32_16x16x16bf16_1k(vhi, pfrag, oB, 0, 0, 0);
    }
  }
  // l[q=n]: reduce partial sums across the 4 quads
  float l = lsum;
  l += __shfl_xor(l, 16, 64);
  l += __shfl_xor(l, 32, 64);
  // ---- merge halves: half1 writes partials (ox layout), half0 adds ----
  float* ox  = FUSE ? (extraf + 1200) : extraf;   // [1280] = 4 x 320
  float* oxw = ox + sub * 320;
  if (half) {
#pragma unroll
    for (int r = 0; r < 4; ++r) oxw[n * 20 + quad * 4 + r] = oA[r];
    if (quad == 0) {
#pragma unroll
      for (int r = 0; r < 4; ++r) oxw[n * 20 + 16 + r] = oB[r];
      mrgL[sub * 16 + n] = l;
    }
  }
  __syncthreads();
  if (!half) {
#pragma unroll
    for (int r = 0; r < 4; ++r) oA[r] += oxw[n * 20 + quad * 4 + r];
    if (quad == 0) {
#pragma unroll
      for (int r = 0; r < 4; ++r) oB[r] += oxw[n * 20 + 16 + r];
    }
    l += mrgL[sub * 16 + n];                  // broadcast read per n
    const float inv = 1.f / l;
    // overwrite own region with normalized O (same addrs each lane read)
#pragma unroll
    for (int r = 0; r < 4; ++r) oxw[n * 20 + quad * 4 + r] = oA[r] * inv;
    if (quad == 0) {
#pragma unroll
      for (int r = 0; r < 4; ++r) oxw[n * 20 + 16 + r] = oB[r] * inv;
    }
  }
  if (FUSE) {
    if (!half) {
      float* pw = extraf;
      __asm__ volatile("s_waitcnt lgkmcnt(0)" ::: "memory");  // wave LDS RAW
      const int row  = lane >> 2;     // 0..15
      const int part = lane & 3;      // cols 5*part .. 5*part+4
      float x[D_];
#pragma unroll
      for (int i = 0; i < D_; ++i) x[i] = oxw[row * 20 + i];
      float qv[5], kv[5], vv[5];
#pragma unroll
      for (int jj = 0; jj < 5; ++jj) { qv[jj] = 0.f; kv[jj] = 0.f; vv[jj] = 0.f; }
#pragma unroll
      for (int i = 0; i < D_; ++i) {
        const float xi = x[i];
#pragma unroll
        for (int jj = 0; jj < 5; ++jj) {
          const int j = 5 * part + jj;
          kv[jj] += xi * pw[i * 20 + j];          // K block
          qv[jj] += xi * pw[400 + i * 20 + j];    // Q block
          vv[jj] += xi * pw[800 + i * 20 + j];    // V block
        }
      }
      const float sc = 0.22360679774997896f;
      const int rg = b * 1024 + qbase + row;
      const int s  = rg & 1023;
#pragma unroll
      for (int jj = 0; jj < 5; ++jj) {
        const int j = 5 * part + jj;
        Kb2[(size_t)rg * 32 + j] = f2bf(kv[jj]);
        Qb2[(size_t)rg * 32 + j] = f2bf(qv[jj] * sc);
        Vt2[(size_t)b * 32768 + (size_t)j * 1024 + s] = f2bf(vv[jj]);
      }
      if (part == 0) {
#pragma unroll
        for (int u = 0; u < 6; ++u)
          *(unsigned*)(Kb2 + (size_t)rg * 32 + 20 + 2 * u) = 0u;
      } else if (part == 1) {
#pragma unroll
        for (int u = 0; u < 6; ++u)
          *(unsigned*)(Qb2 + (size_t)rg * 32 + 20 + 2 * u) = 0u;
      }
    }
  } else {
    // ---- fused composed-dense partial over this block's 64 rows ----
    __syncthreads();                     // normalized ox visible to all
    float acc[10];
#pragma unroll
    for (int j = 0; j < 10; ++j) acc[j] = 0.f;
    const int base = q0 * 20;
    if (tid < 256) {
#pragma unroll
      for (int k = 0; k < 5; ++k) {
        const int il = tid + 256 * k;
        const float xv = ox[il];
#pragma unroll
        for (int j = 0; j < 10; ++j)
          acc[j] += xv * W1T[(size_t)j * 20480 + base + il];  // lane-coalesced
      }
    }
    // wave butterfly reduce (tid>=256 contribute zeros)
#pragma unroll
    for (int off = 1; off < 64; off <<= 1) {
#pragma unroll
      for (int j = 0; j < 10; ++j) acc[j] += __shfl_xor(acc[j], off, 64);
    }
    if (tid < 256 && lane == 0) {
#pragma unroll
      for (int j = 0; j < 10; ++j) red2[w * 10 + j] = acc[j];
    }
    __syncthreads();
    if (tid < 10) {
      float s2 = red2[tid] + red2[10 + tid] + red2[20 + tid] + red2[30 + tid];
      atomicAdd(&outp[b * 10 + tid], s2);   // out pre-initialized with bias
    }
  }
}

extern "C" void kernel_launch(void* const* d_in, const int* in_sizes, int n_in,
                              void* d_out, int out_size, void* d_ws, size_t ws_size,
                              hipStream_t stream) {
  const int*   inp = (const int*)d_in[0];
  const float* cw1 = (const float*)d_in[1];
  const float* cb1 = (const float*)d_in[2];
  const float* cw2 = (const float*)d_in[3];
  const float* cb2 = (const float*)d_in[4];
  const float* cw3 = (const float*)d_in[5];
  const float* cb3 = (const float*)d_in[6];
  const float* a1K = (const float*)d_in[7];
  const float* a1Q = (const float*)d_in[8];
  const float* a1V = (const float*)d_in[9];
  const float* a2K = (const float*)d_in[10];
  const float* a2Q = (const float*)d_in[11];
  const float* a2V = (const float*)d_in[12];
  const float* a3K = (const float*)d_in[13];
  const float* a3Q = (const float*)d_in[14];
  const float* a3V = (const float*)d_in[15];
  const float* dw1 = (const float*)d_in[16];
  const float* db1 = (const float*)d_in[17];
  const float* dw2 = (const float*)d_in[18];
  const float* db2 = (const float*)d_in[19];
  const float* dw3 = (const float*)d_in[20];
  const float* db3 = (const float*)d_in[21];
  float* outp = (float*)d_out;

  // workspace layout (float units) — R23/R19 verbatim
  float* wsf = (float*)d_ws;
  ushort_t* qbA  = (ushort_t*)(wsf);            // [65536][32] bf16  [0 .. 1,048,576)
  ushort_t* kbA  = (ushort_t*)(wsf + 1048576);  //                   [1,048,576 .. 2,097,152)
  ushort_t* vtA  = (ushort_t*)(wsf + 2097152);  // [B,32,S]          [2,097,152 .. 3,145,728)
  float*    w1t  = wsf + 4466688;               // [10,20480]        ends 4,671,488
  ushort_t* qbB  = (ushort_t*)(wsf + 4671488);  // ends 5,195,776
  ushort_t* kbB  = (ushort_t*)(wsf + 5712384);  // B-buffers overlap dead c2 region
  ushort_t* vtB  = (ushort_t*)(wsf + 6760960);  //   (c2 consumed before attn1 writes B)
  float*    c2   = wsf + 5242880;               // [B,4,2048,5]      [5,242,880 .. 7,864,320)

  conv12_kernel<<<512, 256, 0, stream>>>(inp, cw1, cb1, cw2, cb2, c2, dw1,
                                         w1t, db1, dw2, db2, dw3, db3, outp);

  conv3_proj_kernel<<<256, 256, 0, stream>>>(c2, cw3, cb3, a1K, a1Q, a1V,
                                             qbA, kbA, vtA);
  // attn1: reads A, fused proj(layer2) -> B
  attn_kernel<true><<<1024, 512, 0, stream>>>(
      qbA, kbA, vtA, a2K, a2Q, a2V, qbB, kbB, vtB, nullptr, nullptr);
  // attn2: reads B, fused proj(layer3) -> A
  attn_kernel<true><<<1024, 512, 0, stream>>>(
      qbB, kbB, vtB, a3K, a3Q, a3V, qbA, kbA, vtA, nullptr, nullptr);
  // attn3: reads A, fused composed-dense -> atomicAdd outp
  attn_kernel<false><<<1024, 512, 0, stream>>>(
      qbA, kbA, vtA, nullptr, nullptr, nullptr, nullptr, nullptr, nullptr,
      w1t, outp);
}